// Round 4
// baseline (325.088 us; speedup 1.0000x reference)
//
#include <hip/hip_runtime.h>
#include <hip/hip_bf16.h>

#define B_ 8
#define S_ 1024
#define DIN 1024
#define HEADS 16
#define FILTERS 64
#define HF 1024

typedef __attribute__((ext_vector_type(8))) short bf16x8;
typedef __attribute__((ext_vector_type(4))) float f32x4;
typedef __attribute__((ext_vector_type(16))) float f32x16;
typedef __attribute__((ext_vector_type(4))) unsigned int u32x4;

__device__ __forceinline__ unsigned short f2bf(float f) {
  unsigned int u = __float_as_uint(f);
  u += 0x7fff + ((u >> 16) & 1);   // round-to-nearest-even
  return (unsigned short)(u >> 16);
}
__device__ __forceinline__ float bf2f(unsigned short h) {
  return __uint_as_float(((unsigned int)h) << 16);
}
__device__ __forceinline__ void gl_lds16(const void* g, void* l) {
  __builtin_amdgcn_global_load_lds(
      (const __attribute__((address_space(1))) unsigned int*)g,
      (__attribute__((address_space(3))) unsigned int*)l, 16, 0, 0);
}

// ---------------------------------------------------------------- fp32 -> bf16 A convert
__global__ __launch_bounds__(256) void convert_a(
    const float* __restrict__ q, const float* __restrict__ k,
    const float* __restrict__ v, unsigned short* __restrict__ out) {
  int z = blockIdx.y;
  const float* src = z == 0 ? q : (z == 1 ? k : v);
  unsigned short* dst = out + (size_t)z * 8388608;
  int i = blockIdx.x * 256 + threadIdx.x;
  #pragma unroll
  for (int u = 0; u < 4; ++u) {
    int idx = i + u * 524288;
    float4 x = ((const float4*)src)[idx];
    ushort4 h = {f2bf(x.x), f2bf(x.y), f2bf(x.z), f2bf(x.w)};
    ((ushort4*)dst)[idx] = h;
  }
}

// ---------------------------------------------------------------- prep
// WT[z][n][k] = W_z[k][n] as bf16 ; W1fT[f][c] = W1[c][f] + (c%64==f)
__global__ __launch_bounds__(256) void prep_weights(
    const float* __restrict__ Wq, const float* __restrict__ Wk,
    const float* __restrict__ Wv, const float* __restrict__ W1,
    unsigned short* __restrict__ WT, unsigned short* __restrict__ W1fT) {
  __shared__ float tl[64][65];
  int t = threadIdx.x;
  int z = blockIdx.y;
  if (z < 3) {
    const float* W = z == 0 ? Wq : (z == 1 ? Wk : Wv);
    unsigned short* out = WT + (size_t)z * 1024 * 1024;
    int k0 = (blockIdx.x >> 4) << 6;
    int n0 = (blockIdx.x & 15) << 6;
    for (int i = 0; i < 16; ++i) {
      int idx = t + i * 256; int r = idx >> 6, c = idx & 63;
      tl[r][c] = W[(size_t)(k0 + r) * HF + n0 + c];
    }
    __syncthreads();
    for (int i = 0; i < 16; ++i) {
      int idx = t + i * 256; int r = idx >> 6, c = idx & 63;
      out[(size_t)(n0 + r) * DIN + k0 + c] = f2bf(tl[c][r]);
    }
  } else {
    if (blockIdx.x >= 16) return;
    int k0 = blockIdx.x << 6;
    for (int i = 0; i < 16; ++i) {
      int idx = t + i * 256; int r = idx >> 6, c = idx & 63;
      tl[r][c] = W1[(size_t)(k0 + r) * FILTERS + c];
    }
    __syncthreads();
    for (int i = 0; i < 16; ++i) {
      int idx = t + i * 256; int f = idx >> 6, c = idx & 63;
      float v = tl[c][f] + ((((k0 + c) & 63) == f) ? 1.0f : 0.0f);
      W1fT[(size_t)f * HF + k0 + c] = f2bf(v);
    }
  }
}

// ---------------------------------------------------------------- QKV GEMM (m97-style)
// Pre-swizzled global source: LDS slot (row,c8) holds global chunk (row, c8^(row&7));
// reads XOR the same bits -> 16-way ds_read conflict becomes 2-way (free).
__global__ __launch_bounds__(256) void qkv_gemm(
    const unsigned short* __restrict__ Abf, const unsigned short* __restrict__ WT,
    const float* __restrict__ bq, const float* __restrict__ bk,
    const float* __restrict__ bv, unsigned short* __restrict__ outq) {
  __shared__ char lsA[16384];   // [128][64] bf16
  __shared__ char lsB[16384];
  int tid = threadIdx.x;
  int v = (blockIdx.x & 7) * 192 + (blockIdx.x >> 3);
  int z = v >> 9; int r2 = v & 511; int bm = r2 >> 3; int bn = r2 & 7;
  const unsigned short* A = Abf + (size_t)z * 8388608;
  const float* bias = z == 0 ? bq : (z == 1 ? bk : bv);
  const unsigned short* Bm = WT + (size_t)z * 1048576;
  unsigned short* out = outq + (size_t)z * 8388608;
  int lane = tid & 63, wv = tid >> 6;
  int wr = wv >> 1, wc = wv & 1;
  f32x4 acc[4][4] = {};
  for (int k0 = 0; k0 < DIN; k0 += 64) {
    __syncthreads();
    #pragma unroll
    for (int i = 0; i < 4; ++i) {
      int idx = tid + i * 256;
      int row = idx >> 3, c8 = (idx & 7) ^ (row & 7);   // pre-swizzled source
      gl_lds16(A + (size_t)(bm * 128 + row) * DIN + k0 + c8 * 8, lsA + idx * 16);
      gl_lds16(Bm + (size_t)(bn * 128 + row) * DIN + k0 + c8 * 8, lsB + idx * 16);
    }
    __syncthreads();
    #pragma unroll
    for (int kk = 0; kk < 2; ++kk) {
      int cb = kk * 64 + ((lane >> 4) << 4);
      bf16x8 af[4], bfr[4];
      #pragma unroll
      for (int m = 0; m < 4; ++m) {
        int row = wr * 64 + m * 16 + (lane & 15);
        af[m] = *(const bf16x8*)(lsA + row * 128 + (cb ^ ((row & 7) << 4)));
      }
      #pragma unroll
      for (int n = 0; n < 4; ++n) {
        int row = wc * 64 + n * 16 + (lane & 15);
        bfr[n] = *(const bf16x8*)(lsB + row * 128 + (cb ^ ((row & 7) << 4)));
      }
      #pragma unroll
      for (int m = 0; m < 4; ++m)
        #pragma unroll
        for (int n = 0; n < 4; ++n)
          acc[m][n] = __builtin_amdgcn_mfma_f32_16x16x32_bf16(af[m], bfr[n], acc[m][n], 0, 0, 0);
    }
  }
  float mul = (z == 1) ? 0.18033688011112042f : 1.0f;  // 0.125*log2(e) folded into K
  #pragma unroll
  for (int n = 0; n < 4; ++n) {
    int col = bn * 128 + wc * 64 + n * 16 + (lane & 15);
    float bb = bias[col];
    int h = col >> 6, f = col & 63;
    #pragma unroll
    for (int m = 0; m < 4; ++m)
      #pragma unroll
      for (int r = 0; r < 4; ++r) {
        int rowg = bm * 128 + wr * 64 + m * 16 + ((lane >> 4) << 2) + r;
        int b = rowg >> 10, s = rowg & 1023;
        out[(size_t)(((b * HEADS + h) << 10) + s) * 64 + f] = f2bf((acc[m][n][r] + bb) * mul);
      }
  }
}

// ---------------------------------------------------------------- V transpose
__global__ __launch_bounds__(256) void transpose_v(
    const unsigned short* __restrict__ v_bh, unsigned short* __restrict__ vT_bh) {
  __shared__ unsigned short tl[64][68];
  int t = threadIdx.x;
  int bh = blockIdx.y;
  int s0 = blockIdx.x << 6;
  const unsigned short* src = v_bh + ((size_t)bh * S_ + s0) * 64;
  #pragma unroll
  for (int i = 0; i < 2; ++i) {
    int idx = t + i * 256; int row = idx >> 3, c8 = idx & 7;
    int4 v = *(const int4*)(src + row * 64 + c8 * 8);
    const unsigned short* pv = (const unsigned short*)&v;
    #pragma unroll
    for (int e = 0; e < 8; ++e) tl[row][c8 * 8 + e] = pv[e];
  }
  __syncthreads();
  unsigned short* dst = vT_bh + (size_t)bh * 64 * S_;
  #pragma unroll
  for (int i = 0; i < 16; ++i) {
    int idx = t + i * 256; int f = idx >> 6, sl = idx & 63;
    dst[(size_t)f * S_ + s0 + sl] = tl[sl][f];
  }
}

// ---------------------------------------------------------------- attention (m214-style)
// + fused GroupNorm1 channel stats (atomics) in the epilogue.
__global__ __launch_bounds__(256, 3) void attn_kernel(
    const unsigned short* __restrict__ q_bh, const unsigned short* __restrict__ k_bh,
    const unsigned short* __restrict__ vT_bh, unsigned short* __restrict__ en_f,
    float* __restrict__ gsum, float* __restrict__ gss) {
  __shared__ char lsQ[16384];            // [128 q][64 d] swizzled
  __shared__ char lsK[2][8192];          // [64 kpos][64 d]
  __shared__ char lsV[2][8192];          // [64 f][64 kpos]
  __shared__ float lsL[4][32];
  int tid = threadIdx.x, lane = tid & 63, wv = tid >> 6;
  int l31 = lane & 31, hi = lane >> 5;
  int id = blockIdx.x;                   // 1024 = 8 xcd * 16 bh * 8 qt
  int r_ = id >> 3;
  int bh = ((id & 7) << 4) | (r_ >> 3);
  int qt = r_ & 7;
  int b = bh >> 4, h = bh & 15;
  int s0 = qt << 7;                      // 128 q rows per block
  const unsigned short* qp = q_bh + ((size_t)bh * S_ + s0) * 64;
  const unsigned short* kp0 = k_bh + (size_t)bh * 65536;
  const unsigned short* vp0 = vT_bh + (size_t)bh * 65536;   // [64 f][1024 s]

  #pragma unroll
  for (int i = 0; i < 4; ++i) {
    int idx = tid + i * 256; int row = idx >> 3, c8 = idx & 7;
    int4 vq = *(const int4*)(qp + row * 64 + c8 * 8);
    *(int4*)(lsQ + row * 128 + ((c8 * 16) ^ ((row & 7) << 4))) = vq;
  }
  #pragma unroll
  for (int i = 0; i < 2; ++i) {
    int idx = tid + i * 256; int row = idx >> 3, c8 = idx & 7;
    int4 vk = *(const int4*)(kp0 + idx * 8);
    int4 vv = *(const int4*)(vp0 + (size_t)row * S_ + c8 * 8);
    int off = row * 128 + ((c8 * 16) ^ ((row & 7) << 4));
    *(int4*)(lsK[0] + off) = vk;
    *(int4*)(lsV[0] + off) = vv;
  }
  __syncthreads();

  bf16x8 qf[4];
  int qrow0 = 32 * wv + l31;
  #pragma unroll
  for (int dc = 0; dc < 4; ++dc)
    qf[dc] = *(const bf16x8*)(lsQ + qrow0 * 128 + ((dc * 32 + hi * 16) ^ ((qrow0 & 7) << 4)));

  f32x16 o0 = {}, o1 = {};
  float l_part = 0.f;
  for (int t = 0; t < 16; ++t) {
    char* Kb = lsK[t & 1];
    char* Vb = lsV[t & 1];
    int4 kr[2], vr[2];
    if (t < 15) {
      #pragma unroll
      for (int i = 0; i < 2; ++i) {
        int idx = tid + i * 256; int row = idx >> 3, c8 = idx & 7;
        kr[i] = *(const int4*)(kp0 + (t + 1) * 4096 + idx * 8);
        vr[i] = *(const int4*)(vp0 + (size_t)row * S_ + (t + 1) * 64 + c8 * 8);
      }
    }
    f32x16 sa = {}, sb = {};
    __builtin_amdgcn_s_setprio(1);
    #pragma unroll
    for (int dc = 0; dc < 4; ++dc) {
      int cb = dc * 32 + hi * 16;
      int swz = (l31 & 7) << 4;
      bf16x8 k0 = *(const bf16x8*)(Kb + l31 * 128 + (cb ^ swz));
      bf16x8 k1 = *(const bf16x8*)(Kb + (32 + l31) * 128 + (cb ^ swz));
      sa = __builtin_amdgcn_mfma_f32_32x32x16_bf16(k0, qf[dc], sa, 0, 0, 0);
      sb = __builtin_amdgcn_mfma_f32_32x32x16_bf16(k1, qf[dc], sb, 0, 0, 0);
    }
    __builtin_amdgcn_s_setprio(0);
    #pragma unroll
    for (int r = 0; r < 16; ++r) {
      float ea, eb;
      asm("v_exp_f32 %0, %1" : "=v"(ea) : "v"(sa[r]));
      asm("v_exp_f32 %0, %1" : "=v"(eb) : "v"(sb[r]));
      sa[r] = ea; sb[r] = eb;
      l_part += ea + eb;
    }
    bf16x8 paf[4];
    #pragma unroll
    for (int c = 0; c < 4; ++c) {
      int base = (c & 1) * 8;
      float e0 = (c < 2) ? sa[base + 0] : sb[base + 0];
      float e1 = (c < 2) ? sa[base + 1] : sb[base + 1];
      float e2 = (c < 2) ? sa[base + 2] : sb[base + 2];
      float e3 = (c < 2) ? sa[base + 3] : sb[base + 3];
      float e4 = (c < 2) ? sa[base + 4] : sb[base + 4];
      float e5 = (c < 2) ? sa[base + 5] : sb[base + 5];
      float e6 = (c < 2) ? sa[base + 6] : sb[base + 6];
      float e7 = (c < 2) ? sa[base + 7] : sb[base + 7];
      unsigned int X1, X2, Y1, Y2;
      asm("v_cvt_pk_bf16_f32 %0, %1, %2" : "=v"(X1) : "v"(e0), "v"(e1));
      asm("v_cvt_pk_bf16_f32 %0, %1, %2" : "=v"(X2) : "v"(e2), "v"(e3));
      asm("v_cvt_pk_bf16_f32 %0, %1, %2" : "=v"(Y1) : "v"(e4), "v"(e5));
      asm("v_cvt_pk_bf16_f32 %0, %1, %2" : "=v"(Y2) : "v"(e6), "v"(e7));
      asm("v_permlane32_swap_b32 %0, %1" : "+v"(X1), "+v"(Y1));
      asm("v_permlane32_swap_b32 %0, %1" : "+v"(X2), "+v"(Y2));
      u32x4 w4 = {X1, X2, Y1, Y2};
      paf[c] = __builtin_bit_cast(bf16x8, w4);
    }
    __builtin_amdgcn_s_setprio(1);
    #pragma unroll
    for (int c = 0; c < 4; ++c) {
      int cb = c * 32 + hi * 16;
      int swz = (l31 & 7) << 4;
      bf16x8 v0 = *(const bf16x8*)(Vb + l31 * 128 + (cb ^ swz));
      bf16x8 v1 = *(const bf16x8*)(Vb + (32 + l31) * 128 + (cb ^ swz));
      o0 = __builtin_amdgcn_mfma_f32_32x32x16_bf16(paf[c], v0, o0, 0, 0, 0);
      o1 = __builtin_amdgcn_mfma_f32_32x32x16_bf16(paf[c], v1, o1, 0, 0, 0);
    }
    __builtin_amdgcn_s_setprio(0);
    if (t < 15) {
      #pragma unroll
      for (int i = 0; i < 2; ++i) {
        int idx = tid + i * 256; int row = idx >> 3, c8 = idx & 7;
        int off = row * 128 + ((c8 * 16) ^ ((row & 7) << 4));
        *(int4*)(lsK[(t + 1) & 1] + off) = kr[i];
        *(int4*)(lsV[(t + 1) & 1] + off) = vr[i];
      }
    }
    __syncthreads();
  }
  // epilogue: l-reduce, normalize, +q residual, store, fused gn1 stats
  float lf = l_part + __shfl_xor(l_part, 32);
  if (lane < 32) lsL[wv][l31] = lf;
  float s10 = 0.f, s20 = 0.f, s11 = 0.f, s21 = 0.f;
  #pragma unroll
  for (int r = 0; r < 16; ++r) {
    int q = (r & 3) + 8 * (r >> 2) + 4 * hi;
    float linv = 1.0f / lsL[wv][q];
    int qrow = 32 * wv + q;
    int srow = s0 + qrow;
    unsigned short* op = en_f + ((size_t)(b * S_ + srow)) * HF + h * 64;
    int swz = (qrow & 7) << 4;
    float qr0 = bf2f(*(const unsigned short*)(lsQ + qrow * 128 + ((l31 * 2) ^ swz)));
    float qr1 = bf2f(*(const unsigned short*)(lsQ + qrow * 128 + (((32 + l31) * 2) ^ swz)));
    float v0 = o0[r] * linv + qr0;
    float v1 = o1[r] * linv + qr1;
    op[l31] = f2bf(v0);
    op[32 + l31] = f2bf(v1);
    s10 += v0; s20 += v0 * v0;
    s11 += v1; s21 += v1 * v1;
  }
  // combine the two hi-halves (each covered 16 of the wave's 32 q rows)
  s10 += __shfl_xor(s10, 32); s20 += __shfl_xor(s20, 32);
  s11 += __shfl_xor(s11, 32); s21 += __shfl_xor(s21, 32);
  if (hi == 0) {
    int c0 = (b << 10) + (h << 6) + l31;
    atomicAdd(&gsum[c0], s10);      atomicAdd(&gss[c0], s20);
    atomicAdd(&gsum[c0 + 32], s11); atomicAdd(&gss[c0 + 32], s21);
  }
}

// ---------------------------------------------------------------- gn1 finalize
__global__ __launch_bounds__(256) void gn1_finalize(
    const float* __restrict__ gsum, const float* __restrict__ gss,
    float* __restrict__ meanf, float* __restrict__ rstdf) {
  int i = blockIdx.x * 256 + threadIdx.x;   // 8192
  float m = gsum[i] * (1.0f / 1024.0f);
  float v = gss[i] * (1.0f / 1024.0f) - m * m;
  meanf[i] = m;
  rstdf[i] = rsqrtf(v + 1e-3f);
}

// ---------------------------------------------------------------- fused gn1_norm + dense + gn2_stats
__global__ __launch_bounds__(256) void dense_fused(
    const unsigned short* __restrict__ en_f, const float* __restrict__ meanf,
    const float* __restrict__ rstdf, const unsigned short* __restrict__ W1fT,
    const float* __restrict__ b1, float* __restrict__ out1,
    float* __restrict__ g2sum, float* __restrict__ g2ss) {
  __shared__ char lsA[64 * 128], lsB[64 * 128];
  int tid = threadIdx.x, lane = tid & 63, wv = tid >> 6;
  int bm = blockIdx.x;          // 128 blocks x 64 rows
  int b = bm >> 4;
  f32x4 acc[4] = {};
  for (int k0 = 0; k0 < HF; k0 += 64) {
    __syncthreads();
    #pragma unroll
    for (int i = 0; i < 2; ++i) {
      int idx = tid + i * 256; int row = idx >> 3, c8 = idx & 7;
      int4 v = *(const int4*)(en_f + (size_t)(bm * 64 + row) * HF + k0 + c8 * 8);
      const unsigned short* vs = (const unsigned short*)&v;
      const float* mp = meanf + (b << 10) + k0 + c8 * 8;
      const float* rp = rstdf + (b << 10) + k0 + c8 * 8;
      unsigned short hh[8];
      #pragma unroll
      for (int e = 0; e < 8; ++e)
        hh[e] = f2bf((bf2f(vs[e]) - mp[e]) * rp[e]);
      *(int4*)(lsA + row * 128 + ((c8 * 16) ^ ((row & 7) << 4))) = *(const int4*)hh;
    }
    #pragma unroll
    for (int i = 0; i < 2; ++i) {
      int idx = tid + i * 256; int row = idx >> 3, c8 = idx & 7;
      int4 v = *(const int4*)(W1fT + (size_t)row * HF + k0 + c8 * 8);
      *(int4*)(lsB + row * 128 + ((c8 * 16) ^ ((row & 7) << 4))) = v;
    }
    __syncthreads();
    #pragma unroll
    for (int kk = 0; kk < 2; ++kk) {
      int cb = kk * 64 + ((lane >> 4) << 4);
      int arow = wv * 16 + (lane & 15);
      bf16x8 af = *(const bf16x8*)(lsA + arow * 128 + (cb ^ ((arow & 7) << 4)));
      #pragma unroll
      for (int j = 0; j < 4; ++j) {
        int row = j * 16 + (lane & 15);
        bf16x8 bfr = *(const bf16x8*)(lsB + row * 128 + (cb ^ ((row & 7) << 4)));
        acc[j] = __builtin_amdgcn_mfma_f32_16x16x32_bf16(af, bfr, acc[j], 0, 0, 0);
      }
    }
  }
  float s1[4], s2[4];
  #pragma unroll
  for (int j = 0; j < 4; ++j) {
    int f = j * 16 + (lane & 15);
    float bb = b1[f];
    s1[j] = 0.f; s2[j] = 0.f;
    #pragma unroll
    for (int r = 0; r < 4; ++r) {
      int rowg = bm * 64 + wv * 16 + ((lane >> 4) << 2) + r;
      float val = acc[j][r] + bb;
      out1[(size_t)rowg * 64 + f] = val;
      s1[j] += val; s2[j] += val * val;
    }
  }
  #pragma unroll
  for (int j = 0; j < 4; ++j) {
    s1[j] += __shfl_xor(s1[j], 16); s1[j] += __shfl_xor(s1[j], 32);
    s2[j] += __shfl_xor(s2[j], 16); s2[j] += __shfl_xor(s2[j], 32);
  }
  if (lane < 16) {
    #pragma unroll
    for (int j = 0; j < 4; ++j) {
      int f = j * 16 + lane;
      atomicAdd(&g2sum[(b << 6) + f], s1[j]);
      atomicAdd(&g2ss[(b << 6) + f], s2[j]);
    }
  }
}

// ---------------------------------------------------------------- GroupNorm2 normalize
__global__ __launch_bounds__(256) void gn2_norm(
    const float* __restrict__ out1, const float* __restrict__ g2sum,
    const float* __restrict__ g2ss, float* __restrict__ dout) {
  const float invS = 1.0f / 1024.0f;
  int gs = gridDim.x * blockDim.x;
  for (int i = blockIdx.x * 256 + threadIdx.x; i < 131072; i += gs) {
    float4 x = ((const float4*)out1)[i];
    int lin = i * 4;
    int f = lin & 63;
    int b = lin >> 16;
    float vals[4] = {x.x, x.y, x.z, x.w};
    float o[4];
    #pragma unroll
    for (int e = 0; e < 4; ++e) {
      float mean = g2sum[b * 64 + f + e] * invS;
      float var = g2ss[b * 64 + f + e] * invS - mean * mean;
      float rstd = rsqrtf(var + 1e-3f);
      o[e] = (vals[e] - mean) * rstd;
    }
    float4 y = {o[0], o[1], o[2], o[3]};
    ((float4*)dout)[i] = y;
  }
}

// ---------------------------------------------------------------- launch
extern "C" void kernel_launch(void* const* d_in, const int* in_sizes, int n_in,
                              void* d_out, int out_size, void* d_ws, size_t ws_size,
                              hipStream_t stream) {
  const float* qw = (const float*)d_in[0];
  const float* kw = (const float*)d_in[1];
  const float* vw = (const float*)d_in[2];
  const float* Wq = (const float*)d_in[3];
  const float* bq = (const float*)d_in[4];
  const float* Wk = (const float*)d_in[5];
  const float* bk = (const float*)d_in[6];
  const float* Wv = (const float*)d_in[7];
  const float* bv = (const float*)d_in[8];
  const float* W1 = (const float*)d_in[9];
  const float* b1 = (const float*)d_in[10];

  char* ws = (char*)d_ws;
  unsigned short* WT   = (unsigned short*)(ws);                   // 6 MB
  unsigned short* W1fT = (unsigned short*)(ws + 6291456);         // 128 KB
  unsigned short* qb   = (unsigned short*)(ws + 6422528);         // q,k,v: 3 x 16 MB bf16
  unsigned short* vT   = (unsigned short*)(ws + 56754176);        // 16 MB
  unsigned short* Abf  = (unsigned short*)(ws + 73531392);        // 48 MB (dead after qkv_gemm)
  unsigned short* en_f = (unsigned short*)(ws + 73531392);        // 16 MB bf16 (aliases Abf)
  float* gsum          = (float*)(ws + 123863040);                // 32 KB
  float* gss           = (float*)(ws + 123895808);                // 32 KB
  float* meanf         = (float*)(ws + 123928576);                // 32 KB
  float* rstdf         = (float*)(ws + 123961344);                // 32 KB
  float* out1          = (float*)(ws + 123994112);                // 2 MB
  float* g2sum         = (float*)(ws + 126091264);                // 2 KB
  float* g2ss          = (float*)(ws + 126093312);                // 2 KB

  hipMemsetAsync(gsum, 0, 65536, stream);   // gsum + gss
  hipMemsetAsync(g2sum, 0, 4096, stream);   // g2sum + g2ss

  convert_a<<<dim3(2048, 3), 256, 0, stream>>>(qw, kw, vw, Abf);
  prep_weights<<<dim3(256, 4), 256, 0, stream>>>(Wq, Wk, Wv, W1, WT, W1fT);
  qkv_gemm<<<1536, 256, 0, stream>>>(Abf, WT, bq, bk, bv, qb);
  transpose_v<<<dim3(16, 128), 256, 0, stream>>>(qb + 2 * 8388608, vT);
  attn_kernel<<<1024, 256, 0, stream>>>(qb, qb + 8388608, vT, en_f, gsum, gss);
  gn1_finalize<<<32, 256, 0, stream>>>(gsum, gss, meanf, rstdf);
  dense_fused<<<128, 256, 0, stream>>>(en_f, meanf, rstdf, W1fT, b1, out1, g2sum, g2ss);
  gn2_norm<<<512, 256, 0, stream>>>(out1, g2sum, g2ss, (float*)d_out);
}

// Round 6
// 295.235 us; speedup vs baseline: 1.1011x; 1.1011x over previous
//
#include <hip/hip_runtime.h>
#include <hip/hip_bf16.h>

#define B_ 8
#define S_ 1024
#define DIN 1024
#define HEADS 16
#define FILTERS 64
#define HF 1024

typedef __attribute__((ext_vector_type(8))) short bf16x8;
typedef __attribute__((ext_vector_type(4))) float f32x4;
typedef __attribute__((ext_vector_type(16))) float f32x16;
typedef __attribute__((ext_vector_type(4))) unsigned int u32x4;

__device__ __forceinline__ unsigned short f2bf(float f) {
  unsigned int u = __float_as_uint(f);
  u += 0x7fff + ((u >> 16) & 1);   // round-to-nearest-even
  return (unsigned short)(u >> 16);
}
__device__ __forceinline__ float bf2f(unsigned short h) {
  return __uint_as_float(((unsigned int)h) << 16);
}
__device__ __forceinline__ void gl_lds16(const void* g, void* l) {
  __builtin_amdgcn_global_load_lds(
      (const __attribute__((address_space(1))) unsigned int*)g,
      (__attribute__((address_space(3))) unsigned int*)l, 16, 0, 0);
}

// ---------------------------------------------------------------- prep_all
// id < 6144        : A convert  (z = id>>11, x = id&2047)
// 6144 <= id <6912 : W-transpose (zz = (id-6144)>>8, x = &255)
// 6912 <= id <6928 : W1fT (+identity fold)
// 6928 <= id <6996 : zero stats region (17408 floats)
__global__ __launch_bounds__(256) void prep_all(
    const float* __restrict__ qw, const float* __restrict__ kw,
    const float* __restrict__ vw,
    const float* __restrict__ Wq, const float* __restrict__ Wk,
    const float* __restrict__ Wv, const float* __restrict__ W1,
    unsigned short* __restrict__ Abf, unsigned short* __restrict__ WT,
    unsigned short* __restrict__ W1fT, float* __restrict__ statsz) {
  __shared__ float tl[64][65];
  int t = threadIdx.x;
  int id = blockIdx.x;
  if (id < 6144) {
    int z = id >> 11, x = id & 2047;
    const float* src = z == 0 ? qw : (z == 1 ? kw : vw);
    unsigned short* dst = Abf + (size_t)z * 8388608;
    int i = x * 256 + t;
    #pragma unroll
    for (int u = 0; u < 4; ++u) {
      int idx = i + u * 524288;
      float4 xv = ((const float4*)src)[idx];
      ushort4 h = {f2bf(xv.x), f2bf(xv.y), f2bf(xv.z), f2bf(xv.w)};
      ((ushort4*)dst)[idx] = h;
    }
  } else if (id < 6912) {
    int r0 = id - 6144;
    int z = r0 >> 8, x = r0 & 255;
    const float* W = z == 0 ? Wq : (z == 1 ? Wk : Wv);
    unsigned short* out = WT + (size_t)z * 1048576;
    int k0 = (x >> 4) << 6;
    int n0 = (x & 15) << 6;
    for (int i = 0; i < 16; ++i) {
      int idx = t + i * 256; int r = idx >> 6, c = idx & 63;
      tl[r][c] = W[(size_t)(k0 + r) * HF + n0 + c];
    }
    __syncthreads();
    for (int i = 0; i < 16; ++i) {
      int idx = t + i * 256; int r = idx >> 6, c = idx & 63;
      out[(size_t)(n0 + r) * DIN + k0 + c] = f2bf(tl[c][r]);
    }
  } else if (id < 6928) {
    int k0 = (id - 6912) << 6;
    for (int i = 0; i < 16; ++i) {
      int idx = t + i * 256; int r = idx >> 6, c = idx & 63;
      tl[r][c] = W1[(size_t)(k0 + r) * FILTERS + c];
    }
    __syncthreads();
    for (int i = 0; i < 16; ++i) {
      int idx = t + i * 256; int f = idx >> 6, c = idx & 63;
      float v = tl[c][f] + ((((k0 + c) & 63) == f) ? 1.0f : 0.0f);
      W1fT[(size_t)f * HF + k0 + c] = f2bf(v);
    }
  } else {
    int idx = (id - 6928) * 256 + t;
    if (idx < 17408) statsz[idx] = 0.f;
  }
}

// ---------------------------------------------------------------- QKV GEMM (m97-style)
// z==0/1 -> [B][H][S][F] bf16 (K pre-scaled by 0.125*log2e); z==2 -> vT [B][H][F][S]
__global__ __launch_bounds__(256) void qkv_gemm(
    const unsigned short* __restrict__ Abf, const unsigned short* __restrict__ WT,
    const float* __restrict__ bq, const float* __restrict__ bk,
    const float* __restrict__ bv, unsigned short* __restrict__ outq,
    unsigned short* __restrict__ vT) {
  __shared__ char ls[32768];
  char* lsA = ls;
  char* lsB = ls + 16384;
  int tid = threadIdx.x;
  int v = (blockIdx.x & 7) * 192 + (blockIdx.x >> 3);
  int z = v >> 9; int r2 = v & 511; int bm = r2 >> 3; int bn = r2 & 7;
  const unsigned short* A = Abf + (size_t)z * 8388608;
  const float* bias = z == 0 ? bq : (z == 1 ? bk : bv);
  const unsigned short* Bm = WT + (size_t)z * 1048576;
  int lane = tid & 63, wv = tid >> 6;
  int wr = wv >> 1, wc = wv & 1;
  f32x4 acc[4][4] = {};
  for (int k0 = 0; k0 < DIN; k0 += 64) {
    __syncthreads();
    #pragma unroll
    for (int i = 0; i < 4; ++i) {
      int idx = tid + i * 256;
      int row = idx >> 3, c8 = (idx & 7) ^ (row & 7);   // pre-swizzled source
      gl_lds16(A + (size_t)(bm * 128 + row) * DIN + k0 + c8 * 8, lsA + idx * 16);
      gl_lds16(Bm + (size_t)(bn * 128 + row) * DIN + k0 + c8 * 8, lsB + idx * 16);
    }
    __syncthreads();
    #pragma unroll
    for (int kk = 0; kk < 2; ++kk) {
      int cb = kk * 64 + ((lane >> 4) << 4);
      bf16x8 af[4], bfr[4];
      #pragma unroll
      for (int m = 0; m < 4; ++m) {
        int row = wr * 64 + m * 16 + (lane & 15);
        af[m] = *(const bf16x8*)(lsA + row * 128 + (cb ^ ((row & 7) << 4)));
      }
      #pragma unroll
      for (int n = 0; n < 4; ++n) {
        int row = wc * 64 + n * 16 + (lane & 15);
        bfr[n] = *(const bf16x8*)(lsB + row * 128 + (cb ^ ((row & 7) << 4)));
      }
      #pragma unroll
      for (int m = 0; m < 4; ++m)
        #pragma unroll
        for (int n = 0; n < 4; ++n)
          acc[m][n] = __builtin_amdgcn_mfma_f32_16x16x32_bf16(af[m], bfr[n], acc[m][n], 0, 0, 0);
    }
  }
  int b = bm >> 3;
  if (z < 2) {
    unsigned short* out = outq + (size_t)z * 8388608;
    float mul = (z == 1) ? 0.18033688011112042f : 1.0f;  // 0.125*log2(e)
    #pragma unroll
    for (int n = 0; n < 4; ++n) {
      int col = bn * 128 + wc * 64 + n * 16 + (lane & 15);
      float bb = bias[col];
      int h = col >> 6, f = col & 63;
      #pragma unroll
      for (int m = 0; m < 4; ++m)
        #pragma unroll
        for (int r = 0; r < 4; ++r) {
          int rowg = bm * 128 + wr * 64 + m * 16 + ((lane >> 4) << 2) + r;
          int s = rowg & 1023;
          out[(size_t)(((b * HEADS + h) << 10) + s) * 64 + f] = f2bf((acc[m][n][r] + bb) * mul);
        }
    }
  } else {
    // V: transpose through LDS, write vT[b][h][f][s] coalesced along s
    __syncthreads();   // all waves done reading ls
    #pragma unroll
    for (int n = 0; n < 4; ++n) {
      int colL = wc * 64 + n * 16 + (lane & 15);
      float bb = bias[bn * 128 + colL];
      int swz = (colL & 7) << 4;
      #pragma unroll
      for (int m = 0; m < 4; ++m)
        #pragma unroll
        for (int r = 0; r < 4; ++r) {
          int rowL = wr * 64 + m * 16 + ((lane >> 4) << 2) + r;
          *(unsigned short*)(ls + colL * 256 + ((rowL * 2) ^ swz)) = f2bf(acc[m][n][r] + bb);
        }
    }
    __syncthreads();
    int colL = tid >> 1, half = tid & 1;
    int h = bn * 2 + (colL >> 6), f = colL & 63;
    int swz = (colL & 7) << 4;
    unsigned short* dst = vT + ((size_t)(b * HEADS + h) << 16) + f * 1024 + (bm & 7) * 128 + half * 64;
    #pragma unroll
    for (int c8 = 0; c8 < 8; ++c8) {
      int4 vv = *(const int4*)(ls + colL * 256 + ((half * 128 + c8 * 16) ^ swz));
      *(int4*)(dst + c8 * 8) = vv;
    }
  }
}

// ---------------------------------------------------------------- attention (m214-style)
// + fused GroupNorm1 channel stats (atomics) in the epilogue.
__global__ __launch_bounds__(256, 3) void attn_kernel(
    const unsigned short* __restrict__ q_bh, const unsigned short* __restrict__ k_bh,
    const unsigned short* __restrict__ vT_bh, unsigned short* __restrict__ en_f,
    float* __restrict__ gsum, float* __restrict__ gss) {
  __shared__ char lsQ[16384];            // [128 q][64 d] swizzled
  __shared__ char lsK[2][8192];          // [64 kpos][64 d]
  __shared__ char lsV[2][8192];          // [64 f][64 kpos]
  __shared__ float lsL[4][32];
  int tid = threadIdx.x, lane = tid & 63, wv = tid >> 6;
  int l31 = lane & 31, hi = lane >> 5;
  int id = blockIdx.x;                   // 1024 = 8 xcd * 16 bh * 8 qt
  int r_ = id >> 3;
  int bh = ((id & 7) << 4) | (r_ >> 3);
  int qt = r_ & 7;
  int b = bh >> 4, h = bh & 15;
  int s0 = qt << 7;                      // 128 q rows per block
  const unsigned short* qp = q_bh + ((size_t)bh * S_ + s0) * 64;
  const unsigned short* kp0 = k_bh + (size_t)bh * 65536;
  const unsigned short* vp0 = vT_bh + (size_t)bh * 65536;   // [64 f][1024 s]

  #pragma unroll
  for (int i = 0; i < 4; ++i) {
    int idx = tid + i * 256; int row = idx >> 3, c8 = idx & 7;
    int4 vq = *(const int4*)(qp + row * 64 + c8 * 8);
    *(int4*)(lsQ + row * 128 + ((c8 * 16) ^ ((row & 7) << 4))) = vq;
  }
  #pragma unroll
  for (int i = 0; i < 2; ++i) {
    int idx = tid + i * 256; int row = idx >> 3, c8 = idx & 7;
    int4 vk = *(const int4*)(kp0 + idx * 8);
    int4 vv = *(const int4*)(vp0 + (size_t)row * S_ + c8 * 8);
    int off = row * 128 + ((c8 * 16) ^ ((row & 7) << 4));
    *(int4*)(lsK[0] + off) = vk;
    *(int4*)(lsV[0] + off) = vv;
  }
  __syncthreads();

  bf16x8 qf[4];
  int qrow0 = 32 * wv + l31;
  #pragma unroll
  for (int dc = 0; dc < 4; ++dc)
    qf[dc] = *(const bf16x8*)(lsQ + qrow0 * 128 + ((dc * 32 + hi * 16) ^ ((qrow0 & 7) << 4)));

  f32x16 o0 = {}, o1 = {};
  float l_part = 0.f;
  for (int t = 0; t < 16; ++t) {
    char* Kb = lsK[t & 1];
    char* Vb = lsV[t & 1];
    int4 kr[2], vr[2];
    if (t < 15) {
      #pragma unroll
      for (int i = 0; i < 2; ++i) {
        int idx = tid + i * 256; int row = idx >> 3, c8 = idx & 7;
        kr[i] = *(const int4*)(kp0 + (t + 1) * 4096 + idx * 8);
        vr[i] = *(const int4*)(vp0 + (size_t)row * S_ + (t + 1) * 64 + c8 * 8);
      }
    }
    f32x16 sa = {}, sb = {};
    __builtin_amdgcn_s_setprio(1);
    #pragma unroll
    for (int dc = 0; dc < 4; ++dc) {
      int cb = dc * 32 + hi * 16;
      int swz = (l31 & 7) << 4;
      bf16x8 k0 = *(const bf16x8*)(Kb + l31 * 128 + (cb ^ swz));
      bf16x8 k1 = *(const bf16x8*)(Kb + (32 + l31) * 128 + (cb ^ swz));
      sa = __builtin_amdgcn_mfma_f32_32x32x16_bf16(k0, qf[dc], sa, 0, 0, 0);
      sb = __builtin_amdgcn_mfma_f32_32x32x16_bf16(k1, qf[dc], sb, 0, 0, 0);
    }
    __builtin_amdgcn_s_setprio(0);
    #pragma unroll
    for (int r = 0; r < 16; ++r) {
      float ea, eb;
      asm("v_exp_f32 %0, %1" : "=v"(ea) : "v"(sa[r]));
      asm("v_exp_f32 %0, %1" : "=v"(eb) : "v"(sb[r]));
      sa[r] = ea; sb[r] = eb;
      l_part += ea + eb;
    }
    bf16x8 paf[4];
    #pragma unroll
    for (int c = 0; c < 4; ++c) {
      int base = (c & 1) * 8;
      float e0 = (c < 2) ? sa[base + 0] : sb[base + 0];
      float e1 = (c < 2) ? sa[base + 1] : sb[base + 1];
      float e2 = (c < 2) ? sa[base + 2] : sb[base + 2];
      float e3 = (c < 2) ? sa[base + 3] : sb[base + 3];
      float e4 = (c < 2) ? sa[base + 4] : sb[base + 4];
      float e5 = (c < 2) ? sa[base + 5] : sb[base + 5];
      float e6 = (c < 2) ? sa[base + 6] : sb[base + 6];
      float e7 = (c < 2) ? sa[base + 7] : sb[base + 7];
      unsigned int X1, X2, Y1, Y2;
      asm("v_cvt_pk_bf16_f32 %0, %1, %2" : "=v"(X1) : "v"(e0), "v"(e1));
      asm("v_cvt_pk_bf16_f32 %0, %1, %2" : "=v"(X2) : "v"(e2), "v"(e3));
      asm("v_cvt_pk_bf16_f32 %0, %1, %2" : "=v"(Y1) : "v"(e4), "v"(e5));
      asm("v_cvt_pk_bf16_f32 %0, %1, %2" : "=v"(Y2) : "v"(e6), "v"(e7));
      asm("v_permlane32_swap_b32 %0, %1" : "+v"(X1), "+v"(Y1));
      asm("v_permlane32_swap_b32 %0, %1" : "+v"(X2), "+v"(Y2));
      u32x4 w4 = {X1, X2, Y1, Y2};
      paf[c] = __builtin_bit_cast(bf16x8, w4);
    }
    __builtin_amdgcn_s_setprio(1);
    #pragma unroll
    for (int c = 0; c < 4; ++c) {
      int cb = c * 32 + hi * 16;
      int swz = (l31 & 7) << 4;
      bf16x8 v0 = *(const bf16x8*)(Vb + l31 * 128 + (cb ^ swz));
      bf16x8 v1 = *(const bf16x8*)(Vb + (32 + l31) * 128 + (cb ^ swz));
      o0 = __builtin_amdgcn_mfma_f32_32x32x16_bf16(paf[c], v0, o0, 0, 0, 0);
      o1 = __builtin_amdgcn_mfma_f32_32x32x16_bf16(paf[c], v1, o1, 0, 0, 0);
    }
    __builtin_amdgcn_s_setprio(0);
    if (t < 15) {
      #pragma unroll
      for (int i = 0; i < 2; ++i) {
        int idx = tid + i * 256; int row = idx >> 3, c8 = idx & 7;
        int off = row * 128 + ((c8 * 16) ^ ((row & 7) << 4));
        *(int4*)(lsK[(t + 1) & 1] + off) = kr[i];
        *(int4*)(lsV[(t + 1) & 1] + off) = vr[i];
      }
    }
    __syncthreads();
  }
  // epilogue: l-reduce, normalize, +q residual, store, fused gn1 stats
  float lf = l_part + __shfl_xor(l_part, 32);
  if (lane < 32) lsL[wv][l31] = lf;
  float s10 = 0.f, s20 = 0.f, s11 = 0.f, s21 = 0.f;
  #pragma unroll
  for (int r = 0; r < 16; ++r) {
    int q = (r & 3) + 8 * (r >> 2) + 4 * hi;
    float linv = 1.0f / lsL[wv][q];
    int qrow = 32 * wv + q;
    int srow = s0 + qrow;
    unsigned short* op = en_f + ((size_t)(b * S_ + srow)) * HF + h * 64;
    int swz = (qrow & 7) << 4;
    float qr0 = bf2f(*(const unsigned short*)(lsQ + qrow * 128 + ((l31 * 2) ^ swz)));
    float qr1 = bf2f(*(const unsigned short*)(lsQ + qrow * 128 + (((32 + l31) * 2) ^ swz)));
    float v0 = o0[r] * linv + qr0;
    float v1 = o1[r] * linv + qr1;
    op[l31] = f2bf(v0);
    op[32 + l31] = f2bf(v1);
    s10 += v0; s20 += v0 * v0;
    s11 += v1; s21 += v1 * v1;
  }
  s10 += __shfl_xor(s10, 32); s20 += __shfl_xor(s20, 32);
  s11 += __shfl_xor(s11, 32); s21 += __shfl_xor(s21, 32);
  if (hi == 0) {
    int c0 = (b << 10) + (h << 6) + l31;
    atomicAdd(&gsum[c0], s10);      atomicAdd(&gss[c0], s20);
    atomicAdd(&gsum[c0 + 32], s11); atomicAdd(&gss[c0 + 32], s21);
  }
}

// ---------------------------------------------------------------- fused gn1_finalize + gn1_norm + dense + gn2_stats
__global__ __launch_bounds__(256) void dense_fused(
    const unsigned short* __restrict__ en_f, const float* __restrict__ gsum,
    const float* __restrict__ gss, const unsigned short* __restrict__ W1fT,
    const float* __restrict__ b1, float* __restrict__ out1,
    float* __restrict__ g2sum, float* __restrict__ g2ss) {
  __shared__ char lsA[64 * 128], lsB[64 * 128];
  __shared__ float lsMean[1024], lsRstd[1024];
  int tid = threadIdx.x, lane = tid & 63, wv = tid >> 6;
  int bm = blockIdx.x;          // 128 blocks x 64 rows
  int b = bm >> 4;
  const float inv1024 = 1.0f / 1024.0f;
  #pragma unroll
  for (int e = 0; e < 4; ++e) {
    int c = tid * 4 + e;
    float m = gsum[(b << 10) + c] * inv1024;
    float vv = gss[(b << 10) + c] * inv1024 - m * m;
    lsMean[c] = m;
    lsRstd[c] = rsqrtf(vv + 1e-3f);
  }
  f32x4 acc[4] = {};
  for (int k0 = 0; k0 < HF; k0 += 64) {
    __syncthreads();
    #pragma unroll
    for (int i = 0; i < 2; ++i) {
      int idx = tid + i * 256; int row = idx >> 3, c8 = idx & 7;
      int4 v = *(const int4*)(en_f + (size_t)(bm * 64 + row) * HF + k0 + c8 * 8);
      const unsigned short* vs = (const unsigned short*)&v;
      unsigned short hh[8];
      #pragma unroll
      for (int e = 0; e < 8; ++e) {
        int c = k0 + c8 * 8 + e;
        hh[e] = f2bf((bf2f(vs[e]) - lsMean[c]) * lsRstd[c]);
      }
      *(int4*)(lsA + row * 128 + ((c8 * 16) ^ ((row & 7) << 4))) = *(const int4*)hh;
    }
    #pragma unroll
    for (int i = 0; i < 2; ++i) {
      int idx = tid + i * 256; int row = idx >> 3, c8 = idx & 7;
      int4 v = *(const int4*)(W1fT + (size_t)row * HF + k0 + c8 * 8);
      *(int4*)(lsB + row * 128 + ((c8 * 16) ^ ((row & 7) << 4))) = v;
    }
    __syncthreads();
    #pragma unroll
    for (int kk = 0; kk < 2; ++kk) {
      int cb = kk * 64 + ((lane >> 4) << 4);
      int arow = wv * 16 + (lane & 15);
      bf16x8 af = *(const bf16x8*)(lsA + arow * 128 + (cb ^ ((arow & 7) << 4)));
      #pragma unroll
      for (int j = 0; j < 4; ++j) {
        int row = j * 16 + (lane & 15);
        bf16x8 bfr = *(const bf16x8*)(lsB + row * 128 + (cb ^ ((row & 7) << 4)));
        acc[j] = __builtin_amdgcn_mfma_f32_16x16x32_bf16(af, bfr, acc[j], 0, 0, 0);
      }
    }
  }
  float s1[4], s2[4];
  #pragma unroll
  for (int j = 0; j < 4; ++j) {
    int f = j * 16 + (lane & 15);
    float bb = b1[f];
    s1[j] = 0.f; s2[j] = 0.f;
    #pragma unroll
    for (int r = 0; r < 4; ++r) {
      int rowg = bm * 64 + wv * 16 + ((lane >> 4) << 2) + r;
      float val = acc[j][r] + bb;
      out1[(size_t)rowg * 64 + f] = val;
      s1[j] += val; s2[j] += val * val;
    }
  }
  #pragma unroll
  for (int j = 0; j < 4; ++j) {
    s1[j] += __shfl_xor(s1[j], 16); s1[j] += __shfl_xor(s1[j], 32);
    s2[j] += __shfl_xor(s2[j], 16); s2[j] += __shfl_xor(s2[j], 32);
  }
  if (lane < 16) {
    #pragma unroll
    for (int j = 0; j < 4; ++j) {
      int f = j * 16 + lane;
      atomicAdd(&g2sum[(b << 6) + f], s1[j]);
      atomicAdd(&g2ss[(b << 6) + f], s2[j]);
    }
  }
}

// ---------------------------------------------------------------- GroupNorm2 normalize
__global__ __launch_bounds__(256) void gn2_norm(
    const float* __restrict__ out1, const float* __restrict__ g2sum,
    const float* __restrict__ g2ss, float* __restrict__ dout) {
  const float invS = 1.0f / 1024.0f;
  int gs = gridDim.x * blockDim.x;
  for (int i = blockIdx.x * 256 + threadIdx.x; i < 131072; i += gs) {
    float4 x = ((const float4*)out1)[i];
    int lin = i * 4;
    int f = lin & 63;
    int b = lin >> 16;
    float vals[4] = {x.x, x.y, x.z, x.w};
    float o[4];
    #pragma unroll
    for (int e = 0; e < 4; ++e) {
      float mean = g2sum[b * 64 + f + e] * invS;
      float var = g2ss[b * 64 + f + e] * invS - mean * mean;
      float rstd = rsqrtf(var + 1e-3f);
      o[e] = (vals[e] - mean) * rstd;
    }
    float4 y = {o[0], o[1], o[2], o[3]};
    ((float4*)dout)[i] = y;
  }
}

// ---------------------------------------------------------------- launch
extern "C" void kernel_launch(void* const* d_in, const int* in_sizes, int n_in,
                              void* d_out, int out_size, void* d_ws, size_t ws_size,
                              hipStream_t stream) {
  const float* qw = (const float*)d_in[0];
  const float* kw = (const float*)d_in[1];
  const float* vw = (const float*)d_in[2];
  const float* Wq = (const float*)d_in[3];
  const float* bq = (const float*)d_in[4];
  const float* Wk = (const float*)d_in[5];
  const float* bk = (const float*)d_in[6];
  const float* Wv = (const float*)d_in[7];
  const float* bv = (const float*)d_in[8];
  const float* W1 = (const float*)d_in[9];
  const float* b1 = (const float*)d_in[10];

  char* ws = (char*)d_ws;
  unsigned short* WT   = (unsigned short*)(ws);                   // 6 MB
  unsigned short* W1fT = (unsigned short*)(ws + 6291456);         // 128 KB -> 6422528
  unsigned short* qb   = (unsigned short*)(ws + 6422528);         // q,k: 2 x 16 MB -> 39976960
  unsigned short* vT   = (unsigned short*)(ws + 39976960);        // 16 MB -> 56754176
  unsigned short* Abf  = (unsigned short*)(ws + 56754176);        // 48 MB -> 107085824
  unsigned short* en_f = (unsigned short*)(ws + 56754176);        // 16 MB (aliases Abf)
  float* gsum          = (float*)(ws + 107085824);                // 32 KB
  float* gss           = (float*)(ws + 107118592);                // 32 KB
  float* g2sum         = (float*)(ws + 107151360);                // 2 KB
  float* g2ss          = (float*)(ws + 107153408);                // 2 KB  (stats contiguous: 17408 floats)
  float* out1          = (float*)(ws + 107155456);                // 2 MB -> 109252608

  prep_all<<<6996, 256, 0, stream>>>(qw, kw, vw, Wq, Wk, Wv, W1, Abf, WT, W1fT, gsum);
  qkv_gemm<<<1536, 256, 0, stream>>>(Abf, WT, bq, bk, bv, qb, vT);
  attn_kernel<<<1024, 256, 0, stream>>>(qb, qb + 8388608, vT, en_f, gsum, gss);
  dense_fused<<<128, 256, 0, stream>>>(en_f, gsum, gss, W1fT, b1, out1, g2sum, g2ss);
  gn2_norm<<<512, 256, 0, stream>>>(out1, g2sum, g2ss, (float*)d_out);
}